// Round 8
// baseline (225.896 us; speedup 1.0000x reference)
//
#include <hip/hip_runtime.h>
#include <math.h>

// OrbitalCofactorAntiequivarianceLayer kernels for MI355X (gfx950).
// B=4096, NSPIN=2, NPS=16, D=256, NION=8, DIM=3.
//
// R13 -> R14: R13 (W in LDS, x reg->LDS pipeline) got cof_matrix ~70->62us.
// Remaining model: 144 LDS ops/wave (64 x-read + 16 x-write + 64 W-read,
// W 4-way bank-conflicted: stride 16 floats -> cch*1024B = 0 mod 128) ->
// ~25us of per-CU LDS serialization. Fix:
// (1) x fragments loaded DIRECTLY from global (R9 pattern) with explicit
//     1-iter register prefetch. Works now (failed in R9) because W no
//     longer shares the VMEM stream -> no per-sub-iteration vmcnt drain;
//     x offsets fold into the 13-bit imm (one addr reg per r).
// (2) Wp stride 20 floats (80B/row): cch offsets {0,64,0,64} mod 128 ->
//     2-way (free, m136) instead of 4-way.
// LDS ops/wave: 144 -> ~64 conflict-free. FMA order/values unchanged ->
// bit-identical. cof_lu unchanged (~7us). Fills (~156us) are harness-fixed.

// ---------------- kernel 1: M = (x@W + b) * env -> ws ----------------
__global__ __launch_bounds__(256)
void cof_matrix(const float* __restrict__ eq,    // (B,32,256)
                const float* __restrict__ rei,   // (B,32,8,3)
                const float* __restrict__ Wm,    // (2,256,16)
                const float* __restrict__ bb,    // (2,16)
                const float* __restrict__ edim,  // (2,8,16,3,3)
                const float* __restrict__ eion,  // (2,8,16)
                float* __restrict__ ws)          // (8192, 256) = M per pair
{
  __shared__ __align__(16) float Wp[256 * 20];    // W[sp], row stride 20 (20 KB)
  __shared__ __align__(16) float Gl[8 * 6 * 16];  // Gram coeffs, SoA [i][c6][o]
  __shared__ __align__(16) float Ml[4 * 320];     // per-wave M (16 rows x stride 20)

  const int tid   = threadIdx.x;
  const int lane  = tid & 63;
  const int wv    = tid >> 6;
  const int blk   = blockIdx.x;
  const int sp    = blk >> 10;           // spin index
  const int bbase = (blk & 1023) * 4;

  const float* wb = Wm + (size_t)sp * 4096;

  // ---- W -> LDS (coalesced read, stride-20 write), once per block ----
  #pragma unroll
  for (int t = 0; t < 4; ++t) {
    const int idx = t * 256 + tid;       // float4 index over [256][16]
    const int d   = idx >> 2;
    const int c4  = idx & 3;
    float4 v = ((const float4*)wb)[idx];
    *(float4*)(Wp + d * 20 + c4 * 4) = v;
  }

  // ---- Gram precompute: G = A^T A per (i,o), cross terms pre-doubled ----
  if (tid < 128) {
    const int i = tid >> 4, o = tid & 15;
    const float* A = edim + (((size_t)sp * 8 + i) * 16 + o) * 9;
    const float a0=A[0],a1=A[1],a2=A[2],a3=A[3],a4=A[4],a5=A[5],a6=A[6],a7=A[7],a8=A[8];
    float* Gp = Gl + i * 96 + o;
    Gp[0]  = a0*a0 + a3*a3 + a6*a6;
    Gp[16] = a1*a1 + a4*a4 + a7*a7;
    Gp[32] = a2*a2 + a5*a5 + a8*a8;
    Gp[48] = 2.f*(a0*a1 + a3*a4 + a6*a7);
    Gp[64] = 2.f*(a0*a2 + a3*a5 + a6*a8);
    Gp[80] = 2.f*(a1*a2 + a4*a5 + a7*a8);
  }
  __syncthreads();

  const int bidx = bbase + wv;
  const int cch  = lane >> 4;        // K-chunk within a 16-float group
  const int nb   = (lane >> 2) & 3;  // row-tile
  const int ob   = lane & 3;         // col-tile

  // x as float4 rows: row n has 64 float4; lane needs rows 4nb..4nb+3,
  // float4 index q*4+cch within the row. Per-r base is loop-invariant ->
  // one address register, q folds into the load's immediate offset.
  const float4* xq = (const float4*)(eq + ((size_t)bidx * 32 + sp * 16) * 256);
  const float4* xr0 = xq + (4 * nb + 0) * 64 + cch;
  const float4* xr1 = xq + (4 * nb + 1) * 64 + cch;
  const float4* xr2 = xq + (4 * nb + 2) * 64 + cch;
  const float4* xr3 = xq + (4 * nb + 3) * 64 + cch;

  float acc[4][4] = {{0.f,0.f,0.f,0.f},{0.f,0.f,0.f,0.f},
                     {0.f,0.f,0.f,0.f},{0.f,0.f,0.f,0.f}};

  // ---- Phase A: y = xs @ W. x fragments direct from global with 1-iter
  // register prefetch (the ONLY VMEM stream in the loop); W from LDS
  // (lgkm counter, independent). FMA order identical to all prior rounds.
  {
    float4 xf[4], xn[4];
    xf[0] = xr0[0]; xf[1] = xr1[0]; xf[2] = xr2[0]; xf[3] = xr3[0];
    #pragma unroll
    for (int q = 0; q < 16; ++q) {
      if (q < 15) {
        xn[0] = xr0[(q + 1) * 4];
        xn[1] = xr1[(q + 1) * 4];
        xn[2] = xr2[(q + 1) * 4];
        xn[3] = xr3[(q + 1) * 4];
      }
      const int dg = q * 16 + cch * 4;
      float wr4[4][4];
      #pragma unroll
      for (int j = 0; j < 4; ++j) {
        float4 t = *(const float4*)(Wp + (dg + j) * 20 + 4 * ob);
        wr4[j][0]=t.x; wr4[j][1]=t.y; wr4[j][2]=t.z; wr4[j][3]=t.w;
      }
      float xs[4][4];
      #pragma unroll
      for (int r = 0; r < 4; ++r) {
        xs[r][0]=xf[r].x; xs[r][1]=xf[r].y; xs[r][2]=xf[r].z; xs[r][3]=xf[r].w;
      }
      #pragma unroll
      for (int r = 0; r < 4; ++r)
        #pragma unroll
        for (int j = 0; j < 4; ++j)
          #pragma unroll
          for (int c2 = 0; c2 < 4; ++c2)
            acc[r][c2] = fmaf(xs[r][j], wr4[j][c2], acc[r][c2]);
      #pragma unroll
      for (int r = 0; r < 4; ++r) xf[r] = xn[r];
    }
  }

  // reduce over K-chunks (lane bits 4-5)
  #pragma unroll
  for (int r = 0; r < 4; ++r)
    #pragma unroll
    for (int c2 = 0; c2 < 4; ++c2) {
      float v = acc[r][c2];
      v += __shfl_xor(v, 16);
      v += __shfl_xor(v, 32);
      acc[r][c2] = v;
    }

  // y (pre-env) in this wave's LDS slice, 16 rows, stride 20 floats.
  float* Mw = Ml + wv * 320;
  {
    float4 bv = *(const float4*)(bb + sp * 16 + 4 * ob);
    if (lane < 16) {
      #pragma unroll
      for (int r = 0; r < 4; ++r) {
        float4 v = make_float4(acc[r][0] + bv.x, acc[r][1] + bv.y,
                               acc[r][2] + bv.z, acc[r][3] + bv.w);
        *(float4*)(Mw + (4 * nb + r) * 20 + 4 * ob) = v;
      }
    }
  }

  // ---- Phase C: envelope; M = y * env -> ws (coalesced float4 store) ----
  {
    const int n = lane >> 2;           // row 0..15, cols 4*ob..4*ob+3
    const float* rp = rei + ((size_t)bidx * 32 + sp * 16 + n) * 24;
    float rv[24];
    #pragma unroll
    for (int t4 = 0; t4 < 6; ++t4) {
      float4 t = *(const float4*)(rp + t4 * 4);
      rv[t4*4+0]=t.x; rv[t4*4+1]=t.y; rv[t4*4+2]=t.z; rv[t4*4+3]=t.w;
    }
    float4 env = make_float4(0.f, 0.f, 0.f, 0.f);
    #pragma unroll
    for (int i = 0; i < 8; ++i) {
      const float r0 = rv[i*3], r1 = rv[i*3+1], r2 = rv[i*3+2];
      const float rr0 = r0*r0, rr1 = r1*r1, rr2 = r2*r2;
      const float rr3 = r0*r1, rr4 = r0*r2, rr5 = r1*r2;
      const float* Gp = Gl + i * 96 + 4 * ob;
      const float4 q00 = *(const float4*)(Gp);
      const float4 q11 = *(const float4*)(Gp + 16);
      const float4 q22 = *(const float4*)(Gp + 32);
      const float4 q01 = *(const float4*)(Gp + 48);
      const float4 q02 = *(const float4*)(Gp + 64);
      const float4 q12 = *(const float4*)(Gp + 80);
      const float4 io  = *(const float4*)(eion + ((size_t)sp * 8 + i) * 16 + 4 * ob);
#define ENVC(c) { float n2 = q00.c*rr0 + q11.c*rr1 + q22.c*rr2 \
                           + q01.c*rr3 + q02.c*rr4 + q12.c*rr5; \
                  n2 = fmaxf(n2, 0.f); \
                  env.c += __expf(-sqrtf(n2)) * io.c; }
      ENVC(x) ENVC(y) ENVC(z) ENVC(w)
#undef ENVC
    }
    const float* mp = Mw + n * 20 + 4 * ob;
    float4 y = *(const float4*)mp;
    const size_t pair = (size_t)bidx * 2 + sp;
    // lanes 0..63 -> offsets 0,4,...,252: fully coalesced 1KB/wave store
    *(float4*)(ws + pair * 256 + n * 16 + 4 * ob) =
        make_float4(y.x * env.x, y.y * env.y, y.z * env.z, y.w * env.w);
  }
}

// ---------------- kernel 2: cofactor via 16-lane LU ----------------
// One wave per block (64 threads); four 16-lane groups handle FOUR distinct
// pairs. A = M^T, fp32 LU with virtual partial pivoting;
// cof[i] = M[i,0]*det*x[i], x = A^{-1} e0 (= row 0 of M^{-1}).
__global__ __launch_bounds__(64)
void cof_lu(const float* __restrict__ ws,   // (8192, 256)
            float* __restrict__ out)        // (B,2,16) = (8192,16)
{
  const int lane = threadIdx.x;
  const int g  = lane >> 4;        // group -> pair within block
  const int r  = lane & 15;        // my row of A (= column r of M)
  const int gb = lane & 48;        // group base for shuffles
  const size_t pair = (size_t)blockIdx.x * 4 + g;
  const float* mg = ws + pair * 256;

  float a[16];
  #pragma unroll
  for (int c = 0; c < 16; ++c) a[c] = mg[c * 16 + r];

  float det = 1.0f;
  int sign = 0;
  unsigned retired = 0;
  unsigned pp0 = 0, pp1 = 0;       // packed pivot indices, 4 bits each
  int srr = 0;
  float accf = (r == 0) ? 1.0f : 0.0f;  // forward rhs (P e0 component)
  float acc2 = 0.0f;                    // z captured at my retirement

  #pragma unroll
  for (int k = 0; k < 16; ++k) {
    const bool act = ((retired >> r) & 1u) == 0u;
    const float av = act ? fabsf(a[k]) : 0.0f;
    unsigned pk = (__float_as_uint(av) & 0xFFFFFFF0u) | (unsigned)r;
    #pragma unroll
    for (int m = 1; m <= 8; m <<= 1) {
      unsigned o2 = __shfl_xor(pk, m);
      pk = (pk > o2) ? pk : o2;
    }
    const int p = (int)(pk & 15u);
    if (k < 8) pp0 |= (unsigned)p << (4 * k);
    else       pp1 |= (unsigned)p << (4 * (k - 8));
    float pv = __shfl(a[k], gb | p);
    if (fabsf(pv) < 1e-30f) pv = (pv < 0.0f) ? -1e-30f : 1e-30f;
    det *= pv;
    retired |= (1u << p);
    sign ^= (int)(__popc((~retired) & ((1u << p) - 1u)) & 1u);
    if (r == p) srr = k;
    const bool upd = act && (r != p);
    float m2 = 0.0f;
    if (upd) { m2 = a[k] / pv; a[k] = m2; }
    #pragma unroll
    for (int c = k + 1; c < 16; ++c) {
      float bcv = __shfl(a[c], gb | p);
      if (upd) a[c] = fmaf(-m2, bcv, a[c]);
    }
    // fused forward solve L z = P e0
    float zk = __shfl(accf, gb | p);
    if (r == p) acc2 = zk;
    if (upd) accf = fmaf(-m2, zk, accf);
  }
  if (sign) det = -det;

  // backward solve U x = z
  float myx = 0.0f;
  #pragma unroll
  for (int j = 15; j >= 0; --j) {
    float t = acc2 / a[j];                   // valid on pivot lane of step j
    const int pj = (int)(((j >= 8) ? (pp1 >> (4 * (j - 8)))
                                   : (pp0 >> (4 * j))) & 15u);
    float xj = __shfl(t, gb | pj);
    if (srr < j) acc2 = fmaf(-a[j], xj, acc2);
    if (r == j) myx = xj;
  }

  const float mi0 = mg[r * 16];              // M[r][0]
  out[pair * 16 + r] = mi0 * det * myx;      // all 64 lanes: 4 pairs x 16
}

extern "C" void kernel_launch(void* const* d_in, const int* in_sizes, int n_in,
                              void* d_out, int out_size, void* d_ws, size_t ws_size,
                              hipStream_t stream) {
  (void)in_sizes; (void)n_in; (void)out_size; (void)ws_size;
  const float* eq   = (const float*)d_in[0];
  const float* rei  = (const float*)d_in[1];
  const float* Wm   = (const float*)d_in[2];
  const float* bb   = (const float*)d_in[3];
  const float* edim = (const float*)d_in[4];
  const float* eion = (const float*)d_in[5];
  float* out = (float*)d_out;
  float* ws  = (float*)d_ws;   // needs 8192*256*4 = 8 MB
  hipLaunchKernelGGL(cof_matrix, dim3(2048), dim3(256), 0, stream,
                     eq, rei, Wm, bb, edim, eion, ws);
  hipLaunchKernelGGL(cof_lu, dim3(2048), dim3(64), 0, stream, ws, out);
}

// Round 9
// 225.239 us; speedup vs baseline: 1.0029x; 1.0029x over previous
//
#include <hip/hip_runtime.h>
#include <math.h>

// OrbitalCofactorAntiequivarianceLayer kernels for MI355X (gfx950).
// B=4096, NSPIN=2, NPS=16, D=256, NION=8, DIM=3.
//
// R14 -> R15: model that fits all rounds: latency-bound with queue-amplified
// load latency (~3K cyc effective: 900 HBM + ~2K queue at ~25K concurrent
// 256B requests). Every prior version had prefetch depth 1 -> each wave
// serializes 16 x ~3K-cycle waits (lifetime ~54K cyc, 94% stalled,
// VALUBusy 25-47%, no pipe saturated). Fix: register prefetch ring DEPTH 4
// (P0..P3, consume P[q&3] then re-issue for q+4; 12 loads in flight at each
// wait; compiler emits counted vmcnt). Macro-expanded static indexing (no
// scratch). FMA order/operands unchanged -> bit-identical.
// Kept from R13/R14: W in LDS at stride 20 (conflict-free), x fragments
// direct from global, M in LDS only for the 16-row transpose, cof_lu split.

// ---------------- kernel 1: M = (x@W + b) * env -> ws ----------------
__global__ __launch_bounds__(256)
void cof_matrix(const float* __restrict__ eq,    // (B,32,256)
                const float* __restrict__ rei,   // (B,32,8,3)
                const float* __restrict__ Wm,    // (2,256,16)
                const float* __restrict__ bb,    // (2,16)
                const float* __restrict__ edim,  // (2,8,16,3,3)
                const float* __restrict__ eion,  // (2,8,16)
                float* __restrict__ ws)          // (8192, 256) = M per pair
{
  __shared__ __align__(16) float Wp[256 * 20];    // W[sp], row stride 20 (20 KB)
  __shared__ __align__(16) float Gl[8 * 6 * 16];  // Gram coeffs, SoA [i][c6][o]
  __shared__ __align__(16) float Ml[4 * 320];     // per-wave M (16 rows x stride 20)

  const int tid   = threadIdx.x;
  const int lane  = tid & 63;
  const int wv    = tid >> 6;
  const int blk   = blockIdx.x;
  const int sp    = blk >> 10;           // spin index
  const int bbase = (blk & 1023) * 4;

  const float* wb = Wm + (size_t)sp * 4096;

  // ---- W -> LDS (coalesced read, stride-20 write), once per block ----
  #pragma unroll
  for (int t = 0; t < 4; ++t) {
    const int idx = t * 256 + tid;       // float4 index over [256][16]
    const int d   = idx >> 2;
    const int c4  = idx & 3;
    float4 v = ((const float4*)wb)[idx];
    *(float4*)(Wp + d * 20 + c4 * 4) = v;
  }

  // ---- Gram precompute: G = A^T A per (i,o), cross terms pre-doubled ----
  if (tid < 128) {
    const int i = tid >> 4, o = tid & 15;
    const float* A = edim + (((size_t)sp * 8 + i) * 16 + o) * 9;
    const float a0=A[0],a1=A[1],a2=A[2],a3=A[3],a4=A[4],a5=A[5],a6=A[6],a7=A[7],a8=A[8];
    float* Gp = Gl + i * 96 + o;
    Gp[0]  = a0*a0 + a3*a3 + a6*a6;
    Gp[16] = a1*a1 + a4*a4 + a7*a7;
    Gp[32] = a2*a2 + a5*a5 + a8*a8;
    Gp[48] = 2.f*(a0*a1 + a3*a4 + a6*a7);
    Gp[64] = 2.f*(a0*a2 + a3*a5 + a6*a8);
    Gp[80] = 2.f*(a1*a2 + a4*a5 + a7*a8);
  }
  __syncthreads();

  const int bidx = bbase + wv;
  const int cch  = lane >> 4;        // K-chunk within a 16-float group
  const int nb   = (lane >> 2) & 3;  // row-tile
  const int ob   = lane & 3;         // col-tile

  // x as float4 rows: row n has 64 float4; lane needs rows 4nb..4nb+3,
  // float4 index q*4+cch within the row. Per-r base is loop-invariant ->
  // one address register, q folds into the load's immediate offset.
  const float4* xq = (const float4*)(eq + ((size_t)bidx * 32 + sp * 16) * 256);
  const float4* xr0 = xq + (4 * nb + 0) * 64 + cch;
  const float4* xr1 = xq + (4 * nb + 1) * 64 + cch;
  const float4* xr2 = xq + (4 * nb + 2) * 64 + cch;
  const float4* xr3 = xq + (4 * nb + 3) * 64 + cch;

  float acc[4][4] = {{0.f,0.f,0.f,0.f},{0.f,0.f,0.f,0.f},
                     {0.f,0.f,0.f,0.f},{0.f,0.f,0.f,0.f}};

  // ---- Phase A: y = xs @ W. x fragments direct from global with a
  // DEPTH-4 register prefetch ring (the ONLY VMEM stream in the loop);
  // W from LDS (lgkm, independent). FMA order identical to all rounds.
  {
    float4 P0[4], P1[4], P2[4], P3[4];
    // prologue: issue q = 0..3
    P0[0]=xr0[ 0]; P0[1]=xr1[ 0]; P0[2]=xr2[ 0]; P0[3]=xr3[ 0];
    P1[0]=xr0[ 4]; P1[1]=xr1[ 4]; P1[2]=xr2[ 4]; P1[3]=xr3[ 4];
    P2[0]=xr0[ 8]; P2[1]=xr1[ 8]; P2[2]=xr2[ 8]; P2[3]=xr3[ 8];
    P3[0]=xr0[12]; P3[1]=xr1[12]; P3[2]=xr2[12]; P3[3]=xr3[12];

#define GSTEP(q, P)                                                           \
    {                                                                         \
      const int dg = (q) * 16 + cch * 4;                                      \
      float wr4[4][4];                                                        \
      _Pragma("unroll")                                                       \
      for (int j = 0; j < 4; ++j) {                                           \
        float4 t = *(const float4*)(Wp + (dg + j) * 20 + 4 * ob);             \
        wr4[j][0]=t.x; wr4[j][1]=t.y; wr4[j][2]=t.z; wr4[j][3]=t.w;           \
      }                                                                       \
      float xs[4][4];                                                         \
      _Pragma("unroll")                                                       \
      for (int r = 0; r < 4; ++r) {                                           \
        xs[r][0]=P[r].x; xs[r][1]=P[r].y; xs[r][2]=P[r].z; xs[r][3]=P[r].w;   \
      }                                                                       \
      _Pragma("unroll")                                                       \
      for (int r = 0; r < 4; ++r)                                             \
        _Pragma("unroll")                                                     \
        for (int j = 0; j < 4; ++j)                                           \
          _Pragma("unroll")                                                   \
          for (int c2 = 0; c2 < 4; ++c2)                                      \
            acc[r][c2] = fmaf(xs[r][j], wr4[j][c2], acc[r][c2]);              \
    }
#define GLOAD(qn, P)                                                          \
    { P[0]=xr0[(qn)*4]; P[1]=xr1[(qn)*4]; P[2]=xr2[(qn)*4]; P[3]=xr3[(qn)*4]; }

    GSTEP(0,  P0)  GLOAD(4,  P0)
    GSTEP(1,  P1)  GLOAD(5,  P1)
    GSTEP(2,  P2)  GLOAD(6,  P2)
    GSTEP(3,  P3)  GLOAD(7,  P3)
    GSTEP(4,  P0)  GLOAD(8,  P0)
    GSTEP(5,  P1)  GLOAD(9,  P1)
    GSTEP(6,  P2)  GLOAD(10, P2)
    GSTEP(7,  P3)  GLOAD(11, P3)
    GSTEP(8,  P0)  GLOAD(12, P0)
    GSTEP(9,  P1)  GLOAD(13, P1)
    GSTEP(10, P2)  GLOAD(14, P2)
    GSTEP(11, P3)  GLOAD(15, P3)
    GSTEP(12, P0)
    GSTEP(13, P1)
    GSTEP(14, P2)
    GSTEP(15, P3)
#undef GSTEP
#undef GLOAD
  }

  // reduce over K-chunks (lane bits 4-5)
  #pragma unroll
  for (int r = 0; r < 4; ++r)
    #pragma unroll
    for (int c2 = 0; c2 < 4; ++c2) {
      float v = acc[r][c2];
      v += __shfl_xor(v, 16);
      v += __shfl_xor(v, 32);
      acc[r][c2] = v;
    }

  // y (pre-env) in this wave's LDS slice, 16 rows, stride 20 floats.
  float* Mw = Ml + wv * 320;
  {
    float4 bv = *(const float4*)(bb + sp * 16 + 4 * ob);
    if (lane < 16) {
      #pragma unroll
      for (int r = 0; r < 4; ++r) {
        float4 v = make_float4(acc[r][0] + bv.x, acc[r][1] + bv.y,
                               acc[r][2] + bv.z, acc[r][3] + bv.w);
        *(float4*)(Mw + (4 * nb + r) * 20 + 4 * ob) = v;
      }
    }
  }

  // ---- Phase C: envelope; M = y * env -> ws (coalesced float4 store) ----
  {
    const int n = lane >> 2;           // row 0..15, cols 4*ob..4*ob+3
    const float* rp = rei + ((size_t)bidx * 32 + sp * 16 + n) * 24;
    float rv[24];
    #pragma unroll
    for (int t4 = 0; t4 < 6; ++t4) {
      float4 t = *(const float4*)(rp + t4 * 4);
      rv[t4*4+0]=t.x; rv[t4*4+1]=t.y; rv[t4*4+2]=t.z; rv[t4*4+3]=t.w;
    }
    float4 env = make_float4(0.f, 0.f, 0.f, 0.f);
    #pragma unroll
    for (int i = 0; i < 8; ++i) {
      const float r0 = rv[i*3], r1 = rv[i*3+1], r2 = rv[i*3+2];
      const float rr0 = r0*r0, rr1 = r1*r1, rr2 = r2*r2;
      const float rr3 = r0*r1, rr4 = r0*r2, rr5 = r1*r2;
      const float* Gp = Gl + i * 96 + 4 * ob;
      const float4 q00 = *(const float4*)(Gp);
      const float4 q11 = *(const float4*)(Gp + 16);
      const float4 q22 = *(const float4*)(Gp + 32);
      const float4 q01 = *(const float4*)(Gp + 48);
      const float4 q02 = *(const float4*)(Gp + 64);
      const float4 q12 = *(const float4*)(Gp + 80);
      const float4 io  = *(const float4*)(eion + ((size_t)sp * 8 + i) * 16 + 4 * ob);
#define ENVC(c) { float n2 = q00.c*rr0 + q11.c*rr1 + q22.c*rr2 \
                           + q01.c*rr3 + q02.c*rr4 + q12.c*rr5; \
                  n2 = fmaxf(n2, 0.f); \
                  env.c += __expf(-sqrtf(n2)) * io.c; }
      ENVC(x) ENVC(y) ENVC(z) ENVC(w)
#undef ENVC
    }
    const float* mp = Mw + n * 20 + 4 * ob;
    float4 y = *(const float4*)mp;
    const size_t pair = (size_t)bidx * 2 + sp;
    // lanes 0..63 -> offsets 0,4,...,252: fully coalesced 1KB/wave store
    *(float4*)(ws + pair * 256 + n * 16 + 4 * ob) =
        make_float4(y.x * env.x, y.y * env.y, y.z * env.z, y.w * env.w);
  }
}

// ---------------- kernel 2: cofactor via 16-lane LU ----------------
// One wave per block (64 threads); four 16-lane groups handle FOUR distinct
// pairs. A = M^T, fp32 LU with virtual partial pivoting;
// cof[i] = M[i,0]*det*x[i], x = A^{-1} e0 (= row 0 of M^{-1}).
__global__ __launch_bounds__(64)
void cof_lu(const float* __restrict__ ws,   // (8192, 256)
            float* __restrict__ out)        // (B,2,16) = (8192,16)
{
  const int lane = threadIdx.x;
  const int g  = lane >> 4;        // group -> pair within block
  const int r  = lane & 15;        // my row of A (= column r of M)
  const int gb = lane & 48;        // group base for shuffles
  const size_t pair = (size_t)blockIdx.x * 4 + g;
  const float* mg = ws + pair * 256;

  float a[16];
  #pragma unroll
  for (int c = 0; c < 16; ++c) a[c] = mg[c * 16 + r];

  float det = 1.0f;
  int sign = 0;
  unsigned retired = 0;
  unsigned pp0 = 0, pp1 = 0;       // packed pivot indices, 4 bits each
  int srr = 0;
  float accf = (r == 0) ? 1.0f : 0.0f;  // forward rhs (P e0 component)
  float acc2 = 0.0f;                    // z captured at my retirement

  #pragma unroll
  for (int k = 0; k < 16; ++k) {
    const bool act = ((retired >> r) & 1u) == 0u;
    const float av = act ? fabsf(a[k]) : 0.0f;
    unsigned pk = (__float_as_uint(av) & 0xFFFFFFF0u) | (unsigned)r;
    #pragma unroll
    for (int m = 1; m <= 8; m <<= 1) {
      unsigned o2 = __shfl_xor(pk, m);
      pk = (pk > o2) ? pk : o2;
    }
    const int p = (int)(pk & 15u);
    if (k < 8) pp0 |= (unsigned)p << (4 * k);
    else       pp1 |= (unsigned)p << (4 * (k - 8));
    float pv = __shfl(a[k], gb | p);
    if (fabsf(pv) < 1e-30f) pv = (pv < 0.0f) ? -1e-30f : 1e-30f;
    det *= pv;
    retired |= (1u << p);
    sign ^= (int)(__popc((~retired) & ((1u << p) - 1u)) & 1u);
    if (r == p) srr = k;
    const bool upd = act && (r != p);
    float m2 = 0.0f;
    if (upd) { m2 = a[k] / pv; a[k] = m2; }
    #pragma unroll
    for (int c = k + 1; c < 16; ++c) {
      float bcv = __shfl(a[c], gb | p);
      if (upd) a[c] = fmaf(-m2, bcv, a[c]);
    }
    // fused forward solve L z = P e0
    float zk = __shfl(accf, gb | p);
    if (r == p) acc2 = zk;
    if (upd) accf = fmaf(-m2, zk, accf);
  }
  if (sign) det = -det;

  // backward solve U x = z
  float myx = 0.0f;
  #pragma unroll
  for (int j = 15; j >= 0; --j) {
    float t = acc2 / a[j];                   // valid on pivot lane of step j
    const int pj = (int)(((j >= 8) ? (pp1 >> (4 * (j - 8)))
                                   : (pp0 >> (4 * j))) & 15u);
    float xj = __shfl(t, gb | pj);
    if (srr < j) acc2 = fmaf(-a[j], xj, acc2);
    if (r == j) myx = xj;
  }

  const float mi0 = mg[r * 16];              // M[r][0]
  out[pair * 16 + r] = mi0 * det * myx;      // all 64 lanes: 4 pairs x 16
}

extern "C" void kernel_launch(void* const* d_in, const int* in_sizes, int n_in,
                              void* d_out, int out_size, void* d_ws, size_t ws_size,
                              hipStream_t stream) {
  (void)in_sizes; (void)n_in; (void)out_size; (void)ws_size;
  const float* eq   = (const float*)d_in[0];
  const float* rei  = (const float*)d_in[1];
  const float* Wm   = (const float*)d_in[2];
  const float* bb   = (const float*)d_in[3];
  const float* edim = (const float*)d_in[4];
  const float* eion = (const float*)d_in[5];
  float* out = (float*)d_out;
  float* ws  = (float*)d_ws;   // needs 8192*256*4 = 8 MB
  hipLaunchKernelGGL(cof_matrix, dim3(2048), dim3(256), 0, stream,
                     eq, rei, Wm, bb, edim, eion, ws);
  hipLaunchKernelGGL(cof_lu, dim3(2048), dim3(64), 0, stream, ws, out);
}